// Round 1
// baseline (1061.093 us; speedup 1.0000x reference)
//
#include <hip/hip_runtime.h>
#include <math.h>

#define HEADS 4
#define DIM 32
#define FDIM 128  // HEADS*DIM

// ---------------- CSR build ----------------
__global__ void hist_kernel(const int* __restrict__ edges, int* __restrict__ deg,
                            int E, int N) {
  int i = blockIdx.x * blockDim.x + threadIdx.x;
  if (i >= 2 * E) return;
  int r = i / E, e = i - r * E;
  int d = edges[(size_t)r * 2 * E + E + e];
  atomicAdd(&deg[r * N + d], 1);
}

__global__ __launch_bounds__(1024) void scan_kernel(const int* __restrict__ deg,
                                                    int* __restrict__ indptr,
                                                    int* __restrict__ cursor, int N) {
  __shared__ int sums[1024];
  int r = blockIdx.x;
  const int* dg = deg + (size_t)r * N;
  int* ip = indptr + (size_t)r * (N + 1);
  int* cu = cursor + (size_t)r * N;
  int t = threadIdx.x;
  int C = (N + 1023) >> 10;
  int base = t * C;
  int s = 0;
  for (int i = 0; i < C; ++i) {
    int idx = base + i;
    if (idx < N) s += dg[idx];
  }
  sums[t] = s;
  __syncthreads();
  for (int off = 1; off < 1024; off <<= 1) {
    int v = (t >= off) ? sums[t - off] : 0;
    __syncthreads();
    sums[t] += v;
    __syncthreads();
  }
  int run = (t == 0) ? 0 : sums[t - 1];
  for (int i = 0; i < C; ++i) {
    int idx = base + i;
    if (idx < N) {
      int dv = dg[idx];
      ip[idx] = run;
      cu[idx] = run;
      run += dv;
    }
  }
  if (t == 1023) ip[N] = sums[1023];
}

__global__ void scatter_kernel(const int* __restrict__ edges, int* __restrict__ cursor,
                               int* __restrict__ csr_src, int E, int N) {
  int i = blockIdx.x * blockDim.x + threadIdx.x;
  if (i >= 2 * E) return;
  int r = i / E, e = i - r * E;
  const int* ed = edges + (size_t)r * 2 * E;
  int s = ed[e], d = ed[E + e];
  int slot = atomicAdd(&cursor[r * N + d], 1);
  csr_src[(size_t)r * E + slot] = s;
}

// ---------------- matmul: C[N,128] = A[N,128] @ W[128,128] (fp32) ----------------
__global__ __launch_bounds__(256) void matmul_kernel(const float* __restrict__ A,
                                                     const float* __restrict__ W,
                                                     float* __restrict__ C, int N) {
  __shared__ float sW[128 * 128];   // 64 KB
  __shared__ float sA[64 * 132];    // padded stride 132 to break bank conflicts
  int row0 = blockIdx.x * 64;
  for (int i = threadIdx.x * 4; i < 128 * 128; i += 256 * 4)
    *(float4*)(sW + i) = *(const float4*)(W + i);
  int rows = min(64, N - row0);
  for (int i = threadIdx.x * 4; i < rows * 128; i += 256 * 4) {
    float4 v = *(const float4*)(A + (size_t)row0 * 128 + i);
    int rr = i >> 7, cc = i & 127;
    *(float4*)(sA + rr * 132 + cc) = v;
  }
  __syncthreads();
  int cg = threadIdx.x & 15;         // cols cg + 16j, j=0..7 (conflict-free broadcast)
  int tr = (threadIdx.x >> 4) * 4;   // rows tr..tr+3
  float acc[4][8] = {};
  for (int k = 0; k < 128; ++k) {
    float a[4];
#pragma unroll
    for (int i = 0; i < 4; ++i) a[i] = sA[(tr + i) * 132 + k];
#pragma unroll
    for (int j = 0; j < 8; ++j) {
      float w = sW[k * 128 + cg + 16 * j];
#pragma unroll
      for (int i = 0; i < 4; ++i) acc[i][j] = fmaf(a[i], w, acc[i][j]);
    }
  }
  for (int i = 0; i < 4; ++i) {
    int row = row0 + tr + i;
    if (row < N) {
#pragma unroll
      for (int j = 0; j < 8; ++j)
        C[(size_t)row * 128 + cg + 16 * j] = acc[i][j];
    }
  }
}

// ---------------- attention coefficients: el/er [N,4] ----------------
__global__ void attncoef_kernel(const float* __restrict__ feat,
                                const float* __restrict__ al,
                                const float* __restrict__ ar,
                                float* __restrict__ el, float* __restrict__ er, int N) {
  int idx = blockIdx.x * blockDim.x + threadIdx.x;
  if (idx >= N * HEADS) return;
  int h = idx & 3;
  int n = idx >> 2;
  const float4* f = (const float4*)(feat + (size_t)n * FDIM + h * DIM);
  const float4* a = (const float4*)(al + h * DIM);
  const float4* b = (const float4*)(ar + h * DIM);
  float sl = 0.f, sr = 0.f;
#pragma unroll
  for (int j = 0; j < 8; ++j) {
    float4 fv = f[j], av = a[j], bv = b[j];
    sl += fv.x * av.x + fv.y * av.y + fv.z * av.z + fv.w * av.w;
    sr += fv.x * bv.x + fv.y * bv.y + fv.z * bv.z + fv.w * bv.w;
  }
  el[idx] = sl;
  er[idx] = sr;
}

// ---------------- aggregation: one wave per dst node, online softmax ----------------
// lane i handles features 2i, 2i+1 (both in head i/16)
__global__ __launch_bounds__(256) void agg1_kernel(const float* __restrict__ feat,
    const float* __restrict__ el, const float* __restrict__ er,
    const int* __restrict__ indptr, const int* __restrict__ csr_src,
    const float* __restrict__ bias, float* __restrict__ hout, int N) {
  int wv = threadIdx.x >> 6;
  int lane = threadIdx.x & 63;
  int node = blockIdx.x * 4 + wv;
  if (node >= N) return;
  int head = lane >> 4;
  int beg = indptr[node], end = indptr[node + 1];
  float er_h = er[node * 4 + head];
  float m = -1e30f, l = 0.f, a0 = 0.f, a1 = 0.f;
  for (int i = beg; i < end; ++i) {
    int s = csr_src[i];
    float e = el[s * 4 + head] + er_h;
    e = e > 0.f ? e : 0.2f * e;                // LeakyReLU
    float mn = fmaxf(m, e);
    float sc = __expf(m - mn);                 // first iter: exp(-inf)=0
    float p = __expf(e - mn);
    float2 f = *(const float2*)(feat + (size_t)s * FDIM + lane * 2);
    l = l * sc + p;
    a0 = a0 * sc + p * f.x;
    a1 = a1 * sc + p * f.y;
    m = mn;
  }
  float inv = (l > 0.f) ? 1.f / l : 0.f;
  float o0 = a0 * inv, o1 = a1 * inv;
  float2 bv = *(const float2*)(bias + lane * 2);
  float t0 = o0 + bv.x, t1 = o1 + bv.y;
  t0 = t0 > 0.f ? t0 : __expf(t0) - 1.f;       // ELU
  t1 = t1 > 0.f ? t1 : __expf(t1) - 1.f;
  float2* hp = (float2*)(hout + (size_t)node * FDIM + lane * 2);
  float2 hv = *hp;
  hv.x += t0;
  hv.y += t1;
  *hp = hv;
}

__global__ __launch_bounds__(256) void agg2_kernel(const float* __restrict__ feat,
    const float* __restrict__ el, const float* __restrict__ er,
    const int* __restrict__ indptr, const int* __restrict__ csr_src,
    const float* __restrict__ bias, const float* __restrict__ hres,
    float* __restrict__ acc2, int N) {
  int wv = threadIdx.x >> 6;
  int lane = threadIdx.x & 63;
  int node = blockIdx.x * 4 + wv;
  if (node >= N) return;
  int head = lane >> 4;
  int beg = indptr[node], end = indptr[node + 1];
  float er_h = er[node * 4 + head];
  float m = -1e30f, l = 0.f, a0 = 0.f, a1 = 0.f;
  for (int i = beg; i < end; ++i) {
    int s = csr_src[i];
    float e = el[s * 4 + head] + er_h;
    e = e > 0.f ? e : 0.2f * e;
    float mn = fmaxf(m, e);
    float sc = __expf(m - mn);
    float p = __expf(e - mn);
    float2 f = *(const float2*)(feat + (size_t)s * FDIM + lane * 2);
    l = l * sc + p;
    a0 = a0 * sc + p * f.x;
    a1 = a1 * sc + p * f.y;
    m = mn;
  }
  float inv = (l > 0.f) ? 1.f / l : 0.f;
  float o0 = a0 * inv, o1 = a1 * inv;
  float2 bv = *(const float2*)(bias + lane * 2);
  float2 rv = *(const float2*)(hres + (size_t)node * FDIM + lane * 2);
  float2* ap = (float2*)(acc2 + (size_t)node * FDIM + lane * 2);
  float2 av = *ap;
  av.x += o0 + rv.x + bv.x;
  av.y += o1 + rv.y + bv.y;
  *ap = av;
}

// ---------------- final mean over heads ----------------
__global__ void mean_kernel(const float* __restrict__ acc2, float* __restrict__ out, int N) {
  int i = blockIdx.x * blockDim.x + threadIdx.x;
  if (i >= N * 32) return;
  int n = i >> 5, d = i & 31;
  const float* p = acc2 + (size_t)n * FDIM + d;
  out[i] = 0.25f * (p[0] + p[32] + p[64] + p[96]);
}

extern "C" void kernel_launch(void* const* d_in, const int* in_sizes, int n_in,
                              void* d_out, int out_size, void* d_ws, size_t ws_size,
                              hipStream_t stream) {
  const float* x   = (const float*)d_in[0];
  const float* W1  = (const float*)d_in[1];
  const float* al1 = (const float*)d_in[2];
  const float* ar1 = (const float*)d_in[3];
  const float* b1  = (const float*)d_in[4];
  const float* W2  = (const float*)d_in[5];
  const float* al2 = (const float*)d_in[6];
  const float* ar2 = (const float*)d_in[7];
  const float* b2  = (const float*)d_in[8];
  const int* edges = (const int*)d_in[9];
  float* out = (float*)d_out;

  const int N = in_sizes[0] / FDIM;          // 50000
  const int R = in_sizes[1] / (FDIM * FDIM); // 2
  const int E = in_sizes[9] / (2 * R);       // 800000

  char* ws = (char*)d_ws;
  size_t off = 0;
  auto alloc = [&](size_t bytes) {
    char* p = ws + off;
    off += (bytes + 255) & ~(size_t)255;
    return p;
  };
  float* feat  = (float*)alloc((size_t)R * N * FDIM * 4);  // 51.2 MB (reused for layer 2)
  float* el    = (float*)alloc((size_t)R * N * 4 * 4);
  float* er    = (float*)alloc((size_t)R * N * 4 * 4);
  float* h     = (float*)alloc((size_t)N * FDIM * 4);      // layer-1 accum / layer-2 input
  float* acc2  = (float*)alloc((size_t)N * FDIM * 4);
  int* indptr  = (int*)alloc((size_t)R * (N + 1) * 4);
  int* cursor  = (int*)alloc((size_t)R * N * 4);
  int* csr     = (int*)alloc((size_t)R * E * 4);
  int* deg     = (int*)alloc((size_t)R * N * 4);

  hipMemsetAsync(h, 0, (size_t)N * FDIM * 4, stream);
  hipMemsetAsync(acc2, 0, (size_t)N * FDIM * 4, stream);
  hipMemsetAsync(deg, 0, (size_t)R * N * 4, stream);

  // CSR build (edges identical for both layers -> build once)
  hist_kernel<<<(2 * E + 255) / 256, 256, 0, stream>>>(edges, deg, E, N);
  scan_kernel<<<R, 1024, 0, stream>>>(deg, indptr, cursor, N);
  scatter_kernel<<<(2 * E + 255) / 256, 256, 0, stream>>>(edges, cursor, csr, E, N);

  // ---- layer 1 ----
  for (int r = 0; r < R; ++r)
    matmul_kernel<<<(N + 63) / 64, 256, 0, stream>>>(
        x, W1 + (size_t)r * FDIM * FDIM, feat + (size_t)r * N * FDIM, N);
  for (int r = 0; r < R; ++r)
    attncoef_kernel<<<(N * 4 + 255) / 256, 256, 0, stream>>>(
        feat + (size_t)r * N * FDIM, al1 + r * FDIM, ar1 + r * FDIM,
        el + (size_t)r * N * 4, er + (size_t)r * N * 4, N);
  for (int r = 0; r < R; ++r)
    agg1_kernel<<<(N + 3) / 4, 256, 0, stream>>>(
        feat + (size_t)r * N * FDIM, el + (size_t)r * N * 4, er + (size_t)r * N * 4,
        indptr + (size_t)r * (N + 1), csr + (size_t)r * E, b1 + r * FDIM, h, N);

  // ---- layer 2 ----
  for (int r = 0; r < R; ++r)
    matmul_kernel<<<(N + 63) / 64, 256, 0, stream>>>(
        h, W2 + (size_t)r * FDIM * FDIM, feat + (size_t)r * N * FDIM, N);
  for (int r = 0; r < R; ++r)
    attncoef_kernel<<<(N * 4 + 255) / 256, 256, 0, stream>>>(
        feat + (size_t)r * N * FDIM, al2 + r * FDIM, ar2 + r * FDIM,
        el + (size_t)r * N * 4, er + (size_t)r * N * 4, N);
  for (int r = 0; r < R; ++r)
    agg2_kernel<<<(N + 3) / 4, 256, 0, stream>>>(
        feat + (size_t)r * N * FDIM, el + (size_t)r * N * 4, er + (size_t)r * N * 4,
        indptr + (size_t)r * (N + 1), csr + (size_t)r * E, b2 + r * FDIM, h, acc2, N);

  mean_kernel<<<(N * 32 + 255) / 256, 256, 0, stream>>>(acc2, out, N);
}

// Round 2
// 796.564 us; speedup vs baseline: 1.3321x; 1.3321x over previous
//
#include <hip/hip_runtime.h>
#include <math.h>

#define HEADS 4
#define DIM 32
#define FDIM 128  // HEADS*DIM

// ---------------- linked-list adjacency build ----------------
// head[r*N+d] = most recent edge id with dst d (or -1); nxt[r*E+e] = previous one.
// head atomics stay L2-resident (400 KB); nxt writes are edge-indexed -> coalesced.
__global__ void link_kernel(const int* __restrict__ edges, int* __restrict__ head,
                            int* __restrict__ nxt, int E, int N, int R) {
  int i = blockIdx.x * blockDim.x + threadIdx.x;
  if (i >= R * E) return;
  int r = i / E, e = i - r * E;
  int d = edges[(size_t)r * 2 * E + E + e];
  int old = atomicExch(&head[r * N + d], e);
  nxt[i] = old;
}

// ---------------- matmul: C[r][N,128] = A[N,128] @ W[r][128,128] (fp32) ----------------
__global__ __launch_bounds__(256) void matmul_kernel(const float* __restrict__ A,
                                                     const float* __restrict__ Wall,
                                                     float* __restrict__ Call, int N) {
  __shared__ float sW[128 * 128];   // 64 KB
  __shared__ float sA[64 * 132];    // padded stride 132 to break bank conflicts
  int r = blockIdx.y;
  const float* W = Wall + (size_t)r * FDIM * FDIM;
  float* C = Call + (size_t)r * N * FDIM;
  int row0 = blockIdx.x * 64;
  for (int i = threadIdx.x * 4; i < 128 * 128; i += 256 * 4)
    *(float4*)(sW + i) = *(const float4*)(W + i);
  int rows = min(64, N - row0);
  for (int i = threadIdx.x * 4; i < rows * 128; i += 256 * 4) {
    float4 v = *(const float4*)(A + (size_t)row0 * 128 + i);
    int rr = i >> 7, cc = i & 127;
    *(float4*)(sA + rr * 132 + cc) = v;
  }
  __syncthreads();
  int cg = threadIdx.x & 15;         // cols cg + 16j, j=0..7
  int tr = (threadIdx.x >> 4) * 4;   // rows tr..tr+3
  float acc[4][8] = {};
  for (int k = 0; k < 128; ++k) {
    float a[4];
#pragma unroll
    for (int i = 0; i < 4; ++i) a[i] = sA[(tr + i) * 132 + k];
#pragma unroll
    for (int j = 0; j < 8; ++j) {
      float w = sW[k * 128 + cg + 16 * j];
#pragma unroll
      for (int i = 0; i < 4; ++i) acc[i][j] = fmaf(a[i], w, acc[i][j]);
    }
  }
  for (int i = 0; i < 4; ++i) {
    int row = row0 + tr + i;
    if (row < N) {
#pragma unroll
      for (int j = 0; j < 8; ++j)
        C[(size_t)row * 128 + cg + 16 * j] = acc[i][j];
    }
  }
}

// ---------------- attention coefficients: el/er [r][N,4] ----------------
__global__ void attncoef_kernel(const float* __restrict__ feat,
                                const float* __restrict__ al,
                                const float* __restrict__ ar,
                                float* __restrict__ el, float* __restrict__ er, int N) {
  int r = blockIdx.y;
  int idx = blockIdx.x * blockDim.x + threadIdx.x;
  if (idx >= N * HEADS) return;
  int h = idx & 3;
  int n = idx >> 2;
  const float4* f = (const float4*)(feat + (size_t)r * N * FDIM + (size_t)n * FDIM + h * DIM);
  const float4* a = (const float4*)(al + r * FDIM + h * DIM);
  const float4* b = (const float4*)(ar + r * FDIM + h * DIM);
  float sl = 0.f, sr = 0.f;
#pragma unroll
  for (int j = 0; j < 8; ++j) {
    float4 fv = f[j], av = a[j], bv = b[j];
    sl += fv.x * av.x + fv.y * av.y + fv.z * av.z + fv.w * av.w;
    sr += fv.x * bv.x + fv.y * bv.y + fv.z * bv.z + fv.w * bv.w;
  }
  el[(size_t)r * N * 4 + idx] = sl;
  er[(size_t)r * N * 4 + idx] = sr;
}

// ---------------- layer-1 aggregation: one wave per dst node, both relations fused ----
// lane i handles features 2i, 2i+1 (both in head i/16); online softmax over list walk.
__global__ __launch_bounds__(256) void agg1_kernel(const float* __restrict__ feat,
    const float* __restrict__ el, const float* __restrict__ er,
    const int* __restrict__ head, const int* __restrict__ nxt,
    const int* __restrict__ edges, const float* __restrict__ bias,
    float* __restrict__ hout, int N, int E, int R) {
  int wv = threadIdx.x >> 6;
  int lane = threadIdx.x & 63;
  int node = blockIdx.x * 4 + wv;
  if (node >= N) return;
  int hd = lane >> 4;
  float acc0 = 0.f, acc1 = 0.f;
  for (int r = 0; r < R; ++r) {
    const float* f = feat + (size_t)r * N * FDIM;
    const float* elr = el + (size_t)r * N * 4;
    const int* nx = nxt + (size_t)r * E;
    const int* srcs = edges + (size_t)r * 2 * E;  // row 0 = src
    float er_h = er[(size_t)r * N * 4 + node * 4 + hd];
    float m = -1e30f, l = 0.f, a0 = 0.f, a1 = 0.f;
    int e = head[r * N + node];
    while (e >= 0) {
      int en = nx[e];          // issue chain load first
      int s = srcs[e];
      float ee = elr[s * 4 + hd] + er_h;
      ee = ee > 0.f ? ee : 0.2f * ee;            // LeakyReLU
      float mn = fmaxf(m, ee);
      float sc = __expf(m - mn);                 // first iter: exp(-inf)=0
      float p = __expf(ee - mn);
      float2 fv = *(const float2*)(f + (size_t)s * FDIM + lane * 2);
      l = l * sc + p;
      a0 = a0 * sc + p * fv.x;
      a1 = a1 * sc + p * fv.y;
      m = mn;
      e = en;
    }
    float inv = (l > 0.f) ? 1.f / l : 0.f;
    float2 bv = *(const float2*)(bias + r * FDIM + lane * 2);
    float t0 = a0 * inv + bv.x, t1 = a1 * inv + bv.y;
    t0 = t0 > 0.f ? t0 : __expf(t0) - 1.f;       // ELU
    t1 = t1 > 0.f ? t1 : __expf(t1) - 1.f;
    acc0 += t0;
    acc1 += t1;
  }
  *(float2*)(hout + (size_t)node * FDIM + lane * 2) = make_float2(acc0, acc1);
}

// ---------------- layer-2 aggregation + residual + bias + head-mean fused ----------
__global__ __launch_bounds__(256) void agg2_kernel(const float* __restrict__ feat,
    const float* __restrict__ el, const float* __restrict__ er,
    const int* __restrict__ head, const int* __restrict__ nxt,
    const int* __restrict__ edges, const float* __restrict__ bias,
    const float* __restrict__ hres, float* __restrict__ out, int N, int E, int R) {
  int wv = threadIdx.x >> 6;
  int lane = threadIdx.x & 63;
  int node = blockIdx.x * 4 + wv;
  if (node >= N) return;
  int hd = lane >> 4;
  float2 rv = *(const float2*)(hres + (size_t)node * FDIM + lane * 2);
  float acc0 = 0.f, acc1 = 0.f;
  for (int r = 0; r < R; ++r) {
    const float* f = feat + (size_t)r * N * FDIM;
    const float* elr = el + (size_t)r * N * 4;
    const int* nx = nxt + (size_t)r * E;
    const int* srcs = edges + (size_t)r * 2 * E;
    float er_h = er[(size_t)r * N * 4 + node * 4 + hd];
    float m = -1e30f, l = 0.f, a0 = 0.f, a1 = 0.f;
    int e = head[r * N + node];
    while (e >= 0) {
      int en = nx[e];
      int s = srcs[e];
      float ee = elr[s * 4 + hd] + er_h;
      ee = ee > 0.f ? ee : 0.2f * ee;
      float mn = fmaxf(m, ee);
      float sc = __expf(m - mn);
      float p = __expf(ee - mn);
      float2 fv = *(const float2*)(f + (size_t)s * FDIM + lane * 2);
      l = l * sc + p;
      a0 = a0 * sc + p * fv.x;
      a1 = a1 * sc + p * fv.y;
      m = mn;
      e = en;
    }
    float inv = (l > 0.f) ? 1.f / l : 0.f;
    float2 bv = *(const float2*)(bias + r * FDIM + lane * 2);
    acc0 += a0 * inv + rv.x + bv.x;   // o_r + res + b2_r
    acc1 += a1 * inv + rv.y + bv.y;
  }
  // mean over heads: out[n,d] = 0.25 * sum_h acc2[n, h*32+d]
  acc0 += __shfl_xor(acc0, 16);
  acc0 += __shfl_xor(acc0, 32);
  acc1 += __shfl_xor(acc1, 16);
  acc1 += __shfl_xor(acc1, 32);
  if (lane < 16)
    *(float2*)(out + (size_t)node * 32 + lane * 2) = make_float2(acc0 * 0.25f, acc1 * 0.25f);
}

extern "C" void kernel_launch(void* const* d_in, const int* in_sizes, int n_in,
                              void* d_out, int out_size, void* d_ws, size_t ws_size,
                              hipStream_t stream) {
  const float* x   = (const float*)d_in[0];
  const float* W1  = (const float*)d_in[1];
  const float* al1 = (const float*)d_in[2];
  const float* ar1 = (const float*)d_in[3];
  const float* b1  = (const float*)d_in[4];
  const float* W2  = (const float*)d_in[5];
  const float* al2 = (const float*)d_in[6];
  const float* ar2 = (const float*)d_in[7];
  const float* b2  = (const float*)d_in[8];
  const int* edges = (const int*)d_in[9];
  float* out = (float*)d_out;

  const int N = in_sizes[0] / FDIM;          // 50000
  const int R = in_sizes[1] / (FDIM * FDIM); // 2
  const int E = in_sizes[9] / (2 * R);       // 800000

  char* ws = (char*)d_ws;
  size_t off = 0;
  auto alloc = [&](size_t bytes) {
    char* p = ws + off;
    off += (bytes + 255) & ~(size_t)255;
    return p;
  };
  float* feat = (float*)alloc((size_t)R * N * FDIM * 4);  // 51.2 MB
  float* el   = (float*)alloc((size_t)R * N * 4 * 4);
  float* er   = (float*)alloc((size_t)R * N * 4 * 4);
  float* h    = (float*)alloc((size_t)N * FDIM * 4);      // layer-1 out / layer-2 in
  int* head   = (int*)alloc((size_t)R * N * 4);
  int* nxt    = (int*)alloc((size_t)R * E * 4);

  // adjacency build: head=-1 then link (nxt writes coalesced, head atomics L2-resident)
  hipMemsetAsync(head, 0xFF, (size_t)R * N * 4, stream);
  link_kernel<<<(R * E + 255) / 256, 256, 0, stream>>>(edges, head, nxt, E, N, R);

  dim3 mmgrid((N + 63) / 64, R);
  dim3 acgrid((N * HEADS + 255) / 256, R);

  // ---- layer 1 ----
  matmul_kernel<<<mmgrid, 256, 0, stream>>>(x, W1, feat, N);
  attncoef_kernel<<<acgrid, 256, 0, stream>>>(feat, al1, ar1, el, er, N);
  agg1_kernel<<<(N + 3) / 4, 256, 0, stream>>>(feat, el, er, head, nxt, edges, b1, h, N, E, R);

  // ---- layer 2 ----
  matmul_kernel<<<mmgrid, 256, 0, stream>>>(h, W2, feat, N);
  attncoef_kernel<<<acgrid, 256, 0, stream>>>(feat, al2, ar2, el, er, N);
  agg2_kernel<<<(N + 3) / 4, 256, 0, stream>>>(feat, el, er, head, nxt, edges, b2, h, out, N, E, R);
}

// Round 3
// 649.250 us; speedup vs baseline: 1.6343x; 1.2269x over previous
//
#include <hip/hip_runtime.h>
#include <math.h>

#define HEADS 4
#define DIM 32
#define FDIM 128  // HEADS*DIM

__device__ __forceinline__ unsigned short f2bf(float x) {
  unsigned u = __float_as_uint(x);
  u += 0x7FFFu + ((u >> 16) & 1);   // round-to-nearest-even
  return (unsigned short)(u >> 16);
}

// ---------------- linked-list adjacency build ----------------
__global__ void link_kernel(const int* __restrict__ edges, int* __restrict__ head,
                            int* __restrict__ nxt, int E, int N, int R) {
  int i = blockIdx.x * blockDim.x + threadIdx.x;
  if (i >= R * E) return;
  int r = i / E, e = i - r * E;
  int d = edges[(size_t)r * 2 * E + E + e];
  int old = atomicExch(&head[r * N + d], e);
  nxt[i] = old;
}

// ---------------- fused matmul + attn-coef + bf16 cast ----------------
// feat[r] = A @ W[r]  (fp32 accum, bf16 store);  el/er[r] from fp32 accum.
// Block: 64 rows x 128 cols, K streamed in 4 chunks of 32 (~25 KB LDS -> 6 blk/CU).
__global__ __launch_bounds__(256) void mm_fused_kernel(const float* __restrict__ A,
    const float* __restrict__ Wall, const float* __restrict__ al_all,
    const float* __restrict__ ar_all, unsigned short* __restrict__ featb_all,
    float* __restrict__ el_all, float* __restrict__ er_all, int N) {
  __shared__ float sW[32 * 128];   // 16 KB, chunk of W rows k0..k0+31
  __shared__ float sA[32 * 68];    // 8.7 KB, sA[kk*68 + row] (pad 68)
  int r = blockIdx.y;
  const float* W = Wall + (size_t)r * FDIM * FDIM;
  int row0 = blockIdx.x * 64;
  int t = threadIdx.x;
  int cg = t & 15;                 // cols cg + 16j, j=0..7
  int tr = (t >> 4) * 4;           // rows tr..tr+3
  int rr = t >> 2, kq = (t & 3) * 8;  // A-staging assignment
  float acc[4][8] = {};

  for (int kc = 0; kc < 4; ++kc) {
    int k0 = kc * 32;
    if (kc) __syncthreads();
    for (int i = t * 4; i < 32 * 128; i += 1024)
      *(float4*)(sW + i) = *(const float4*)(W + k0 * 128 + i);
    float4 v0 = make_float4(0.f, 0.f, 0.f, 0.f), v1 = v0;
    if (row0 + rr < N) {
      const float* ap = A + (size_t)(row0 + rr) * FDIM + k0 + kq;
      v0 = *(const float4*)(ap);
      v1 = *(const float4*)(ap + 4);
    }
    sA[(kq + 0) * 68 + rr] = v0.x;
    sA[(kq + 1) * 68 + rr] = v0.y;
    sA[(kq + 2) * 68 + rr] = v0.z;
    sA[(kq + 3) * 68 + rr] = v0.w;
    sA[(kq + 4) * 68 + rr] = v1.x;
    sA[(kq + 5) * 68 + rr] = v1.y;
    sA[(kq + 6) * 68 + rr] = v1.z;
    sA[(kq + 7) * 68 + rr] = v1.w;
    __syncthreads();
    for (int kk = 0; kk < 32; ++kk) {
      float4 av = *(const float4*)(sA + kk * 68 + tr);
      float a[4] = {av.x, av.y, av.z, av.w};
#pragma unroll
      for (int j = 0; j < 8; ++j) {
        float w = sW[kk * 128 + cg + 16 * j];
#pragma unroll
        for (int i = 0; i < 4; ++i) acc[i][j] = fmaf(a[i], w, acc[i][j]);
      }
    }
  }

  // ---- epilogue: el/er (fp32) + feat (bf16) ----
  const float* al = al_all + r * FDIM;
  const float* ar = ar_all + r * FDIM;
  float alv[8], arv[8];
#pragma unroll
  for (int j = 0; j < 8; ++j) {
    alv[j] = al[cg + 16 * j];
    arv[j] = ar[cg + 16 * j];
  }
  float elp[4][4], erp[4][4];
#pragma unroll
  for (int i = 0; i < 4; ++i)
#pragma unroll
    for (int h = 0; h < 4; ++h) {
      elp[i][h] = acc[i][2 * h] * alv[2 * h] + acc[i][2 * h + 1] * alv[2 * h + 1];
      erp[i][h] = acc[i][2 * h] * arv[2 * h] + acc[i][2 * h + 1] * arv[2 * h + 1];
    }
#pragma unroll
  for (int off = 1; off < 16; off <<= 1)
#pragma unroll
    for (int i = 0; i < 4; ++i)
#pragma unroll
      for (int h = 0; h < 4; ++h) {
        elp[i][h] += __shfl_xor(elp[i][h], off);
        erp[i][h] += __shfl_xor(erp[i][h], off);
      }
  float* elr = el_all + (size_t)r * N * 4;
  float* err_ = er_all + (size_t)r * N * 4;
  if (cg == 0) {
#pragma unroll
    for (int i = 0; i < 4; ++i) {
      int row = row0 + tr + i;
      if (row < N) {
#pragma unroll
        for (int h = 0; h < 4; ++h) {
          elr[(size_t)row * 4 + h] = elp[i][h];
          err_[(size_t)row * 4 + h] = erp[i][h];
        }
      }
    }
  }
  unsigned short* fb = featb_all + (size_t)r * N * FDIM;
#pragma unroll
  for (int i = 0; i < 4; ++i) {
    int row = row0 + tr + i;
    if (row < N) {
#pragma unroll
      for (int j = 0; j < 8; ++j)
        fb[(size_t)row * FDIM + cg + 16 * j] = f2bf(acc[i][j]);
    }
  }
}

// ---------------- layer-1 aggregation (bf16 feat gather) ----------------
__global__ __launch_bounds__(256) void agg1_kernel(const unsigned short* __restrict__ featb,
    const float* __restrict__ el, const float* __restrict__ er,
    const int* __restrict__ head, const int* __restrict__ nxt,
    const int* __restrict__ edges, const float* __restrict__ bias,
    float* __restrict__ hout, int N, int E, int R) {
  int wv = threadIdx.x >> 6;
  int lane = threadIdx.x & 63;
  int node = blockIdx.x * 4 + wv;
  if (node >= N) return;
  int hd = lane >> 4;
  float acc0 = 0.f, acc1 = 0.f;
  for (int r = 0; r < R; ++r) {
    const unsigned short* f = featb + (size_t)r * N * FDIM;
    const float* elr = el + (size_t)r * N * 4;
    const int* nx = nxt + (size_t)r * E;
    const int* srcs = edges + (size_t)r * 2 * E;
    float er_h = er[(size_t)r * N * 4 + node * 4 + hd];
    float m = -1e30f, l = 0.f, a0 = 0.f, a1 = 0.f;
    int e = head[r * N + node];
    while (e >= 0) {
      int en = nx[e];
      int s = srcs[e];
      float ee = elr[s * 4 + hd] + er_h;
      ee = ee > 0.f ? ee : 0.2f * ee;            // LeakyReLU
      float mn = fmaxf(m, ee);
      float sc = __expf(m - mn);
      float p = __expf(ee - mn);
      unsigned fv = *(const unsigned*)(f + (size_t)s * FDIM + lane * 2);
      float f0 = __uint_as_float(fv << 16);
      float f1 = __uint_as_float(fv & 0xFFFF0000u);
      l = l * sc + p;
      a0 = a0 * sc + p * f0;
      a1 = a1 * sc + p * f1;
      m = mn;
      e = en;
    }
    float inv = (l > 0.f) ? 1.f / l : 0.f;
    float2 bv = *(const float2*)(bias + r * FDIM + lane * 2);
    float t0 = a0 * inv + bv.x, t1 = a1 * inv + bv.y;
    t0 = t0 > 0.f ? t0 : __expf(t0) - 1.f;       // ELU
    t1 = t1 > 0.f ? t1 : __expf(t1) - 1.f;
    acc0 += t0;
    acc1 += t1;
  }
  *(float2*)(hout + (size_t)node * FDIM + lane * 2) = make_float2(acc0, acc1);
}

// ---------------- layer-2 aggregation + residual + bias + head-mean ----------------
__global__ __launch_bounds__(256) void agg2_kernel(const unsigned short* __restrict__ featb,
    const float* __restrict__ el, const float* __restrict__ er,
    const int* __restrict__ head, const int* __restrict__ nxt,
    const int* __restrict__ edges, const float* __restrict__ bias,
    const float* __restrict__ hres, float* __restrict__ out, int N, int E, int R) {
  int wv = threadIdx.x >> 6;
  int lane = threadIdx.x & 63;
  int node = blockIdx.x * 4 + wv;
  if (node >= N) return;
  int hd = lane >> 4;
  float2 rv = *(const float2*)(hres + (size_t)node * FDIM + lane * 2);
  float acc0 = 0.f, acc1 = 0.f;
  for (int r = 0; r < R; ++r) {
    const unsigned short* f = featb + (size_t)r * N * FDIM;
    const float* elr = el + (size_t)r * N * 4;
    const int* nx = nxt + (size_t)r * E;
    const int* srcs = edges + (size_t)r * 2 * E;
    float er_h = er[(size_t)r * N * 4 + node * 4 + hd];
    float m = -1e30f, l = 0.f, a0 = 0.f, a1 = 0.f;
    int e = head[r * N + node];
    while (e >= 0) {
      int en = nx[e];
      int s = srcs[e];
      float ee = elr[s * 4 + hd] + er_h;
      ee = ee > 0.f ? ee : 0.2f * ee;
      float mn = fmaxf(m, ee);
      float sc = __expf(m - mn);
      float p = __expf(ee - mn);
      unsigned fv = *(const unsigned*)(f + (size_t)s * FDIM + lane * 2);
      float f0 = __uint_as_float(fv << 16);
      float f1 = __uint_as_float(fv & 0xFFFF0000u);
      l = l * sc + p;
      a0 = a0 * sc + p * f0;
      a1 = a1 * sc + p * f1;
      m = mn;
      e = en;
    }
    float inv = (l > 0.f) ? 1.f / l : 0.f;
    float2 bv = *(const float2*)(bias + r * FDIM + lane * 2);
    acc0 += a0 * inv + rv.x + bv.x;
    acc1 += a1 * inv + rv.y + bv.y;
  }
  acc0 += __shfl_xor(acc0, 16);
  acc0 += __shfl_xor(acc0, 32);
  acc1 += __shfl_xor(acc1, 16);
  acc1 += __shfl_xor(acc1, 32);
  if (lane < 16)
    *(float2*)(out + (size_t)node * 32 + lane * 2) = make_float2(acc0 * 0.25f, acc1 * 0.25f);
}

extern "C" void kernel_launch(void* const* d_in, const int* in_sizes, int n_in,
                              void* d_out, int out_size, void* d_ws, size_t ws_size,
                              hipStream_t stream) {
  const float* x   = (const float*)d_in[0];
  const float* W1  = (const float*)d_in[1];
  const float* al1 = (const float*)d_in[2];
  const float* ar1 = (const float*)d_in[3];
  const float* b1  = (const float*)d_in[4];
  const float* W2  = (const float*)d_in[5];
  const float* al2 = (const float*)d_in[6];
  const float* ar2 = (const float*)d_in[7];
  const float* b2  = (const float*)d_in[8];
  const int* edges = (const int*)d_in[9];
  float* out = (float*)d_out;

  const int N = in_sizes[0] / FDIM;          // 50000
  const int R = in_sizes[1] / (FDIM * FDIM); // 2
  const int E = in_sizes[9] / (2 * R);       // 800000

  char* ws = (char*)d_ws;
  size_t off = 0;
  auto alloc = [&](size_t bytes) {
    char* p = ws + off;
    off += (bytes + 255) & ~(size_t)255;
    return p;
  };
  unsigned short* featb = (unsigned short*)alloc((size_t)R * N * FDIM * 2);  // 25.6 MB
  float* el = (float*)alloc((size_t)R * N * 4 * 4);
  float* er = (float*)alloc((size_t)R * N * 4 * 4);
  float* h  = (float*)alloc((size_t)N * FDIM * 4);   // layer-1 out / layer-2 in (fp32)
  int* head = (int*)alloc((size_t)R * N * 4);
  int* nxt  = (int*)alloc((size_t)R * E * 4);

  hipMemsetAsync(head, 0xFF, (size_t)R * N * 4, stream);
  link_kernel<<<(R * E + 255) / 256, 256, 0, stream>>>(edges, head, nxt, E, N, R);

  dim3 mmgrid((N + 63) / 64, R);

  // ---- layer 1 ----
  mm_fused_kernel<<<mmgrid, 256, 0, stream>>>(x, W1, al1, ar1, featb, el, er, N);
  agg1_kernel<<<(N + 3) / 4, 256, 0, stream>>>(featb, el, er, head, nxt, edges, b1, h, N, E, R);

  // ---- layer 2 ----
  mm_fused_kernel<<<mmgrid, 256, 0, stream>>>(h, W2, al2, ar2, featb, el, er, N);
  agg2_kernel<<<(N + 3) / 4, 256, 0, stream>>>(featb, el, er, head, nxt, edges, b2, h, out, N, E, R);
}

// Round 4
// 507.296 us; speedup vs baseline: 2.0917x; 1.2798x over previous
//
#include <hip/hip_runtime.h>
#include <math.h>

#define HEADS 4
#define DIM 32
#define FDIM 128  // HEADS*DIM
#define WS 136    // LDS row stride (bf16 elems): 272B = 16B-aligned, breaks worst banking

typedef __attribute__((ext_vector_type(8))) short short8;
typedef __attribute__((ext_vector_type(16))) float float16;

__device__ __forceinline__ unsigned short f2bf(float x) {
  unsigned u = __float_as_uint(x);
  u += 0x7FFFu + ((u >> 16) & 1);   // round-to-nearest-even
  return (unsigned short)(u >> 16);
}

// ---------------- linked-list adjacency build ----------------
__global__ void link_kernel(const int* __restrict__ edges, int* __restrict__ head,
                            int* __restrict__ nxt, int E, int N, int R) {
  int i = blockIdx.x * blockDim.x + threadIdx.x;
  if (i >= R * E) return;
  int r = i / E, e = i - r * E;
  int d = edges[(size_t)r * 2 * E + E + e];
  int old = atomicExch(&head[r * N + d], e);
  nxt[i] = old;
}

// ---------------- MFMA matmul + attn-coef + bf16 feat ----------------
// Block = 256 thr (4 waves), tile 64 rows x 128 cols, full K=128.
// W staged transposed bf16 in LDS (B-frag = contiguous k), A staged bf16.
// Per wave: 2x (32x32) out tiles via v_mfma_f32_32x32x16_bf16, fp32 accum.
// el/er computed from fp32 accumulators (cross-lane reduce), feat stored bf16.
__global__ __launch_bounds__(256) void mm_mfma_kernel(const float* __restrict__ A,
    const float* __restrict__ Wall, const float* __restrict__ al_all,
    const float* __restrict__ ar_all, unsigned short* __restrict__ featb_all,
    float* __restrict__ el_all, float* __restrict__ er_all, int N) {
  __shared__ unsigned short sW[128 * WS];  // Wt[n][k]  (34.8 KB)
  __shared__ unsigned short sA[64 * WS];   // A[m][k]   (17.4 KB)
  int r = blockIdx.y;
  const float* W = Wall + (size_t)r * FDIM * FDIM;
  int row0 = blockIdx.x * 64;
  int t = threadIdx.x;

  // stage W (transpose) fp32 -> bf16
#pragma unroll
  for (int it = 0; it < 16; ++it) {
    int idx = t * 4 + it * 1024;
    int k = idx >> 7, n = idx & 127;
    float4 v = *(const float4*)(W + idx);
    sW[(n + 0) * WS + k] = f2bf(v.x);
    sW[(n + 1) * WS + k] = f2bf(v.y);
    sW[(n + 2) * WS + k] = f2bf(v.z);
    sW[(n + 3) * WS + k] = f2bf(v.w);
  }
  // stage A fp32 -> bf16 (zero-pad tail rows)
#pragma unroll
  for (int it = 0; it < 8; ++it) {
    int idx = t * 4 + it * 1024;
    int row = idx >> 7, k = idx & 127;
    float4 v = make_float4(0.f, 0.f, 0.f, 0.f);
    if (row0 + row < N) v = *(const float4*)(A + (size_t)(row0 + row) * FDIM + k);
    unsigned short* p = sA + row * WS + k;
    p[0] = f2bf(v.x); p[1] = f2bf(v.y); p[2] = f2bf(v.z); p[3] = f2bf(v.w);
  }
  __syncthreads();

  int lane = t & 63, w = t >> 6;
  int m = lane & 31, q = lane >> 5;   // A row / B col within tile; reg-block half
  int m0 = (w & 1) * 32;              // wave's row offset in 64-row block
  int n0 = (w >> 1) * 64;             // wave's col offset (2 tiles of 32)
  float16 acc0 = 0.f, acc1 = 0.f;

#pragma unroll
  for (int kc = 0; kc < 8; ++kc) {
    int k0 = kc * 16;
    short8 a  = *(const short8*)(sA + (m0 + m) * WS + k0 + q * 8);
    short8 b0 = *(const short8*)(sW + (n0 + m) * WS + k0 + q * 8);
    short8 b1 = *(const short8*)(sW + (n0 + 32 + m) * WS + k0 + q * 8);
    acc0 = __builtin_amdgcn_mfma_f32_32x32x16_bf16(a, b0, acc0, 0, 0, 0);
    acc1 = __builtin_amdgcn_mfma_f32_32x32x16_bf16(a, b1, acc1, 0, 0, 0);
  }

  unsigned short* fb = featb_all + (size_t)r * N * FDIM;
  float* elr = el_all + (size_t)r * N * 4;
  float* err_ = er_all + (size_t)r * N * 4;
#pragma unroll
  for (int tile = 0; tile < 2; ++tile) {
    float16 acc = (tile == 0) ? acc0 : acc1;
    int h = (n0 >> 5) + tile;          // head this tile belongs to
    int c = n0 + tile * 32 + m;        // global col
    float alv = al_all[r * FDIM + h * DIM + m];
    float arv = ar_all[r * FDIM + h * DIM + m];
#pragma unroll
    for (int reg = 0; reg < 16; ++reg) {
      float v = acc[reg];
      int rr = (reg & 3) + 8 * (reg >> 2) + 4 * q;   // C-layout row (m74/m101)
      int gr = row0 + m0 + rr;
      float ev = v * alv, rv = v * arv;
#pragma unroll
      for (int off = 1; off < 32; off <<= 1) {       // reduce over 32 cols (lane&31)
        ev += __shfl_xor(ev, off);
        rv += __shfl_xor(rv, off);
      }
      if (gr < N) {
        fb[(size_t)gr * FDIM + c] = f2bf(v);
        if (m == 0) {
          elr[(size_t)gr * 4 + h] = ev;
          err_[(size_t)gr * 4 + h] = rv;
        }
      }
    }
  }
}

// ---------------- layer-1 aggregation: one THREAD per (node, head) ----------------
// 4 adjacent lanes = 4 heads of one node: chain loads coalesce, feat loads tile the
// 256B row. 16 independent chains per wave -> chase latency overlapped.
// Softmax without max-subtraction (pre-activations tame; exp(e) safe in fp32).
__global__ __launch_bounds__(256) void agg1_kernel(const unsigned short* __restrict__ featb,
    const float* __restrict__ el, const float* __restrict__ er,
    const int* __restrict__ head, const int* __restrict__ nxt,
    const int* __restrict__ edges, const float* __restrict__ bias,
    float* __restrict__ hout, int N, int E, int R) {
  int idx = blockIdx.x * 256 + threadIdx.x;
  int node = idx >> 2, hd = idx & 3;
  if (node >= N) return;
  float tot[32];
#pragma unroll
  for (int i = 0; i < 32; ++i) tot[i] = 0.f;
  for (int r = 0; r < R; ++r) {
    const unsigned short* f = featb + (size_t)r * N * FDIM + hd * DIM;
    const float* elr = el + (size_t)r * N * 4;
    const int* nx = nxt + (size_t)r * E;
    const int* srcs = edges + (size_t)r * 2 * E;
    float er_h = er[(size_t)r * N * 4 + node * 4 + hd];
    float l = 0.f;
    float a[32];
#pragma unroll
    for (int i = 0; i < 32; ++i) a[i] = 0.f;
    int e = head[r * N + node];
    while (e >= 0) {
      int en = nx[e];
      int s = srcs[e];
      float ee = elr[s * 4 + hd] + er_h;
      ee = ee > 0.f ? ee : 0.2f * ee;            // LeakyReLU
      float p = __expf(ee);
      const uint4* fp = (const uint4*)(f + (size_t)s * FDIM);
      uint4 u0 = fp[0], u1 = fp[1], u2 = fp[2], u3 = fp[3];
      l += p;
      unsigned uu[16] = {u0.x, u0.y, u0.z, u0.w, u1.x, u1.y, u1.z, u1.w,
                         u2.x, u2.y, u2.z, u2.w, u3.x, u3.y, u3.z, u3.w};
#pragma unroll
      for (int j = 0; j < 16; ++j) {
        float f0 = __uint_as_float(uu[j] << 16);
        float f1 = __uint_as_float(uu[j] & 0xFFFF0000u);
        a[2 * j]     = fmaf(p, f0, a[2 * j]);
        a[2 * j + 1] = fmaf(p, f1, a[2 * j + 1]);
      }
      e = en;
    }
    float inv = (l > 0.f) ? 1.f / l : 0.f;
    const float4* b4 = (const float4*)(bias + r * FDIM + hd * DIM);
#pragma unroll
    for (int g = 0; g < 8; ++g) {
      float4 bv = b4[g];
      float vv[4] = {a[4 * g] * inv + bv.x, a[4 * g + 1] * inv + bv.y,
                     a[4 * g + 2] * inv + bv.z, a[4 * g + 3] * inv + bv.w};
#pragma unroll
      for (int j = 0; j < 4; ++j) {
        float v = vv[j];
        tot[4 * g + j] += v > 0.f ? v : __expf(v) - 1.f;   // ELU
      }
    }
  }
  float4* hp = (float4*)(hout + (size_t)node * FDIM + hd * DIM);
#pragma unroll
  for (int g = 0; g < 8; ++g)
    hp[g] = make_float4(tot[4 * g], tot[4 * g + 1], tot[4 * g + 2], tot[4 * g + 3]);
}

// ---------------- layer-2 aggregation + residual + bias + head-mean ----------------
__global__ __launch_bounds__(256) void agg2_kernel(const unsigned short* __restrict__ featb,
    const float* __restrict__ el, const float* __restrict__ er,
    const int* __restrict__ head, const int* __restrict__ nxt,
    const int* __restrict__ edges, const float* __restrict__ bias,
    const float* __restrict__ hres, float* __restrict__ out, int N, int E, int R) {
  int idx = blockIdx.x * 256 + threadIdx.x;
  int node = idx >> 2, hd = idx & 3;
  if (node >= N) return;
  float tot[32];
  {
    const float4* rv4 = (const float4*)(hres + (size_t)node * FDIM + hd * DIM);
#pragma unroll
    for (int g = 0; g < 8; ++g) {
      float4 rv = rv4[g];
      tot[4 * g] = R * rv.x; tot[4 * g + 1] = R * rv.y;
      tot[4 * g + 2] = R * rv.z; tot[4 * g + 3] = R * rv.w;
    }
  }
  for (int r = 0; r < R; ++r) {
    const unsigned short* f = featb + (size_t)r * N * FDIM + hd * DIM;
    const float* elr = el + (size_t)r * N * 4;
    const int* nx = nxt + (size_t)r * E;
    const int* srcs = edges + (size_t)r * 2 * E;
    float er_h = er[(size_t)r * N * 4 + node * 4 + hd];
    float l = 0.f;
    float a[32];
#pragma unroll
    for (int i = 0; i < 32; ++i) a[i] = 0.f;
    int e = head[r * N + node];
    while (e >= 0) {
      int en = nx[e];
      int s = srcs[e];
      float ee = elr[s * 4 + hd] + er_h;
      ee = ee > 0.f ? ee : 0.2f * ee;
      float p = __expf(ee);
      const uint4* fp = (const uint4*)(f + (size_t)s * FDIM);
      uint4 u0 = fp[0], u1 = fp[1], u2 = fp[2], u3 = fp[3];
      l += p;
      unsigned uu[16] = {u0.x, u0.y, u0.z, u0.w, u1.x, u1.y, u1.z, u1.w,
                         u2.x, u2.y, u2.z, u2.w, u3.x, u3.y, u3.z, u3.w};
#pragma unroll
      for (int j = 0; j < 16; ++j) {
        float f0 = __uint_as_float(uu[j] << 16);
        float f1 = __uint_as_float(uu[j] & 0xFFFF0000u);
        a[2 * j]     = fmaf(p, f0, a[2 * j]);
        a[2 * j + 1] = fmaf(p, f1, a[2 * j + 1]);
      }
      e = en;
    }
    float inv = (l > 0.f) ? 1.f / l : 0.f;
    const float4* b4 = (const float4*)(bias + r * FDIM + hd * DIM);
#pragma unroll
    for (int g = 0; g < 8; ++g) {
      float4 bv = b4[g];
      tot[4 * g]     += a[4 * g] * inv + bv.x;
      tot[4 * g + 1] += a[4 * g + 1] * inv + bv.y;
      tot[4 * g + 2] += a[4 * g + 2] * inv + bv.z;
      tot[4 * g + 3] += a[4 * g + 3] * inv + bv.w;
    }
  }
  // mean over heads: reduce across the 4 lanes of this node's quad
#pragma unroll
  for (int i = 0; i < 32; ++i) {
    float v = tot[i];
    v += __shfl_xor(v, 1);
    v += __shfl_xor(v, 2);
    tot[i] = v * 0.25f;
  }
  if (hd == 0) {
    float4* op = (float4*)(out + (size_t)node * 32);
#pragma unroll
    for (int g = 0; g < 8; ++g)
      op[g] = make_float4(tot[4 * g], tot[4 * g + 1], tot[4 * g + 2], tot[4 * g + 3]);
  }
}

extern "C" void kernel_launch(void* const* d_in, const int* in_sizes, int n_in,
                              void* d_out, int out_size, void* d_ws, size_t ws_size,
                              hipStream_t stream) {
  const float* x   = (const float*)d_in[0];
  const float* W1  = (const float*)d_in[1];
  const float* al1 = (const float*)d_in[2];
  const float* ar1 = (const float*)d_in[3];
  const float* b1  = (const float*)d_in[4];
  const float* W2  = (const float*)d_in[5];
  const float* al2 = (const float*)d_in[6];
  const float* ar2 = (const float*)d_in[7];
  const float* b2  = (const float*)d_in[8];
  const int* edges = (const int*)d_in[9];
  float* out = (float*)d_out;

  const int N = in_sizes[0] / FDIM;          // 50000
  const int R = in_sizes[1] / (FDIM * FDIM); // 2
  const int E = in_sizes[9] / (2 * R);       // 800000

  char* ws = (char*)d_ws;
  size_t off = 0;
  auto alloc = [&](size_t bytes) {
    char* p = ws + off;
    off += (bytes + 255) & ~(size_t)255;
    return p;
  };
  unsigned short* featb = (unsigned short*)alloc((size_t)R * N * FDIM * 2);  // 25.6 MB
  float* el = (float*)alloc((size_t)R * N * 4 * 4);
  float* er = (float*)alloc((size_t)R * N * 4 * 4);
  float* h  = (float*)alloc((size_t)N * FDIM * 4);   // layer-1 out / layer-2 in (fp32)
  int* head = (int*)alloc((size_t)R * N * 4);
  int* nxt  = (int*)alloc((size_t)R * E * 4);

  hipMemsetAsync(head, 0xFF, (size_t)R * N * 4, stream);
  link_kernel<<<(R * E + 255) / 256, 256, 0, stream>>>(edges, head, nxt, E, N, R);

  dim3 mmgrid((N + 63) / 64, R);
  int agrid = (N * HEADS + 255) / 256;

  // ---- layer 1 ----
  mm_mfma_kernel<<<mmgrid, 256, 0, stream>>>(x, W1, al1, ar1, featb, el, er, N);
  agg1_kernel<<<agrid, 256, 0, stream>>>(featb, el, er, head, nxt, edges, b1, h, N, E, R);

  // ---- layer 2 ----
  mm_mfma_kernel<<<mmgrid, 256, 0, stream>>>(h, W2, al2, ar2, featb, el, er, N);
  agg2_kernel<<<agrid, 256, 0, stream>>>(featb, el, er, head, nxt, edges, b2, h, out, N, E, R);
}